// Round 6
// baseline (432.852 us; speedup 1.0000x reference)
//
#include <hip/hip_runtime.h>
#include <hip/hip_bf16.h>

#define B_ 8
#define S_ 128
#define H_ 512
#define E_ 512
#define NST 8
#define R_ 1024         // flat rows
#define N2 2048         // packed GEMM width / T,XO row width
#define KD 512          // GEMM K depth
#define LDA 72          // LDS row pitch in shorts (pad 64 -> 72: 2-way max conflict)
#define TM 64           // GEMM M tile
#define TN 128          // GEMM N tile

typedef __hip_bfloat16 bf16;
typedef __attribute__((ext_vector_type(8))) short v8s;
typedef __attribute__((ext_vector_type(4))) float v4f;

__device__ __forceinline__ float sigm(float x){ return 1.0f/(1.0f + expf(-x)); }
__device__ __forceinline__ float load_in(const void* p, long long i, int isb){
    return isb ? __bfloat162float(((const bf16*)p)[i]) : ((const float*)p)[i];
}
__device__ __forceinline__ int idx_read(const int* p, int j, int is64){
    return is64 ? p[2*j] : p[j];
}
__device__ __forceinline__ unsigned short f2b(float v){
    bf16 b = __float2bfloat16(v);
    return *(unsigned short*)&b;
}

// ---- per-tensor float-storage probe (bf16=1 / fp32=0), validated r4 ----
__global__ void probe_f(const void* t0, const void* t1, const void* t2, const void* t3,
                        const void* t4, const void* t5, const void* t6, const void* t7,
                        const void* t8, const void* t9, const void* t10, const void* t11,
                        const void* t12, const void* t13, const void* t14,
                        int* __restrict__ flags){
    const void* ts[15] = {t0,t1,t2,t3,t4,t5,t6,t7,t8,t9,t10,t11,t12,t13,t14};
    const unsigned short* u = (const unsigned short*)ts[blockIdx.x];
    int t = threadIdx.x;      // 512
    int e = (u[t] >> 7) & 0xFF;
    unsigned long long b = __ballot(e >= 140);
    __shared__ int acc[8];
    if ((t & 63) == 0) acc[t >> 6] = (b != 0ull) ? 1 : 0;
    __syncthreads();
    if (t == 0){
        int any = 0;
        for (int w = 0; w < 8; ++w) any |= acc[w];
        flags[blockIdx.x] = any ? 0 : 1;
    }
}

__global__ void probe_i(const int* __restrict__ ids, const int* __restrict__ tree,
                        int* __restrict__ flags){
    const int* p = (blockIdx.x == 0) ? ids : tree;
    int n = (blockIdx.x == 0) ? 1024 : 2048;
    int t = threadIdx.x;   // 1024
    int nz = 0;
    for (int j = t; j < n; j += 1024)
        if (j & 1) nz |= (p[j] != 0);
    unsigned long long b = __ballot(nz);
    __shared__ int acc[16];
    if ((t & 63) == 0) acc[t >> 6] = (b != 0ull) ? 1 : 0;
    __syncthreads();
    if (t == 0){
        int any = 0;
        for (int w = 0; w < 16; ++w) any |= acc[w];
        flags[16 + blockIdx.x] = any ? 0 : 1;
    }
}

// ---- ballot-based mask + global-compaction rank (r2/r3 cross-validated) ----
__global__ void rank_kernel(const int* __restrict__ tree, int* __restrict__ msk,
                            int* __restrict__ rnk, const int* __restrict__ flags){
    int is64 = flags[17];
    int st = blockIdx.x;
    int t  = threadIdx.x;                 // 0..1023 == b*S+s
    int b = t >> 7, s = t & 127;
    int idx_d = idx_read(tree, ((b*NST + st)*3 + 0)*S_ + s, is64);
    int m = (idx_d != 0) ? 1 : 0;
    unsigned long long bal = __ballot(m);
    int lane = t & 63, wave = t >> 6;
    __shared__ int wtot[16];
    if (lane == 0) wtot[wave] = __popcll(bal);
    __syncthreads();
    int base = 0;
    for (int w = 0; w < wave; ++w) base += wtot[w];
    int rank = base + __popcll(bal & ((1ull << lane) - 1ull));
    msk[st*R_ + t] = m;
    rnk[st*R_ + t] = m ? rank : 0;
}

// ==== CSR inversion of the three scatters (one-time) ====
// list a=0: keyed by rr (scat += T[s][0:512]); a=1: keyed by rl (scat += T[s][512:1024]);
// a=2: keyed by rd (c_scat += f(s)*c_old[s]), payload packs s|rr<<10|rl<<20.
__global__ void csr_count(const int* __restrict__ tree, int* __restrict__ cnt,
                          const int* __restrict__ flags){
    int is64 = flags[17];
    int st = blockIdx.x;
    int t = threadIdx.x;   // 1024
    int b = t >> 7, s = t & 127;
    int base = (b*NST + st)*3*S_;
    int rd = (b<<7) + idx_read(tree, base + s, is64);
    int rr = (b<<7) + idx_read(tree, base + S_ + s, is64);
    int rl = (b<<7) + idx_read(tree, base + 2*S_ + s, is64);
    atomicAdd(&cnt[(0*NST + st)*R_ + rr], 1);
    atomicAdd(&cnt[(1*NST + st)*R_ + rl], 1);
    atomicAdd(&cnt[(2*NST + st)*R_ + rd], 1);
}

__global__ void csr_scan(const int* __restrict__ cnt, int* __restrict__ off,
                         int* __restrict__ cur){
    int st = blockIdx.x, a = blockIdx.y;
    int t = threadIdx.x;   // 1024
    int base = (a*NST + st)*R_;
    __shared__ int sh[R_];
    int v = cnt[base + t];
    sh[t] = v;
    __syncthreads();
    for (int d = 1; d < R_; d <<= 1){
        int x = (t >= d) ? sh[t - d] : 0;
        __syncthreads();
        sh[t] += x;
        __syncthreads();
    }
    int excl = sh[t] - v;
    off[base + t] = excl;
    cur[base + t] = excl;
}

__global__ void csr_fill(const int* __restrict__ tree, int* __restrict__ cur,
                         int* __restrict__ ent, const int* __restrict__ flags){
    int is64 = flags[17];
    int st = blockIdx.x;
    int t = threadIdx.x;   // 1024
    int b = t >> 7, s = t & 127;
    int base = (b*NST + st)*3*S_;
    int rd = (b<<7) + idx_read(tree, base + s, is64);
    int rr = (b<<7) + idx_read(tree, base + S_ + s, is64);
    int rl = (b<<7) + idx_read(tree, base + 2*S_ + s, is64);
    int p0 = atomicAdd(&cur[(0*NST + st)*R_ + rr], 1);
    ent[(0*NST + st)*R_ + p0] = t;
    int p1 = atomicAdd(&cur[(1*NST + st)*R_ + rl], 1);
    ent[(1*NST + st)*R_ + p1] = t;
    int p2 = atomicAdd(&cur[(2*NST + st)*R_ + rd], 1);
    ent[(2*NST + st)*R_ + p2] = t | (rr << 10) | (rl << 20);
}

// ---- weight packs (one-time) ----
__global__ __launch_bounds__(256)
void pack_wxt(const void* __restrict__ Wioux, const void* __restrict__ Wfx,
              unsigned short* __restrict__ WxT, const int* __restrict__ flags){
    int f_wx = flags[1], f_wf = flags[6];
    int n = blockIdx.x*256 + threadIdx.x;
    int k0 = blockIdx.y*8;
    unsigned short tmp[8];
    #pragma unroll
    for (int i = 0; i < 8; ++i){
        float v = (n < 1536) ? load_in(Wioux, (long long)(k0+i)*1536 + n, f_wx)
                             : load_in(Wfx,   (long long)(k0+i)*512 + (n-1536), f_wf);
        tmp[i] = f2b(v);
    }
    *(v8s*)&WxT[(size_t)n*KD + k0] = *(v8s*)tmp;
}

__global__ __launch_bounds__(256)
void pack_wcatt(const void* __restrict__ Wr, const void* __restrict__ Wl,
                const void* __restrict__ W0, const void* __restrict__ W1,
                const void* __restrict__ W2, const void* __restrict__ W3,
                unsigned short* __restrict__ WcatT, const int* __restrict__ flags){
    int fWr=flags[2], fWl=flags[4], fW0=flags[7], fW1=flags[9], fW2=flags[11], fW3=flags[13];
    int n = blockIdx.x*256 + threadIdx.x;
    int k0 = blockIdx.y*8;
    unsigned short tmp[8];
    #pragma unroll
    for (int i = 0; i < 8; ++i){
        long long k = k0 + i;
        float v;
        if      (n <  512) v = load_in(Wr, k*1536 + n, fWr);
        else if (n < 1024) v = load_in(Wl, k*1536 + (n-512), fWl);
        else if (n < 1536) { int c = n-1024; v = load_in(W0, k*512+c, fW0) + load_in(W1, k*512+c, fW1); }
        else               { int c = n-1536; v = load_in(W2, k*512+c, fW2) + load_in(W3, k*512+c, fW3); }
        tmp[i] = f2b(v);
    }
    *(v8s*)&WcatT[(size_t)n*KD + k0] = *(v8s*)tmp;
}

__global__ void pack_bcat(const void* __restrict__ br, const void* __restrict__ bl,
                          const void* __restrict__ b0, const void* __restrict__ b1,
                          const void* __restrict__ b2, const void* __restrict__ b3,
                          float* __restrict__ bcat, const int* __restrict__ flags){
    int fbr=flags[3], fbl=flags[5], fb0=flags[8], fb1=flags[10], fb2=flags[12], fb3=flags[14];
    int n = blockIdx.x*256 + threadIdx.x;   // 2048
    float v;
    if      (n <  512) v = load_in(br, n, fbr);
    else if (n < 1024) v = load_in(bl, n-512, fbl);
    else if (n < 1536) v = load_in(b0, n-1024, fb0) + load_in(b1, n-1024, fb1);
    else               v = load_in(b2, n-1536, fb2) + load_in(b3, n-1536, fb3);
    bcat[n] = v;
}

__global__ __launch_bounds__(256)
void gather_xb(const int* __restrict__ ids, const void* __restrict__ emb,
               unsigned short* __restrict__ xb, const int* __restrict__ flags){
    int f_emb = flags[0], i64 = flags[16];
    int id = blockIdx.x*256 + threadIdx.x;
    int r = id >> 6, c0 = (id & 63)*8;
    long long base = (long long)idx_read(ids, r, i64)*E_ + c0;
    unsigned short tmp[8];
    #pragma unroll
    for (int i = 0; i < 8; ++i) tmp[i] = f2b(load_in(emb, base + i, f_emb));
    *(v8s*)&xb[(size_t)r*KD + c0] = *(v8s*)tmp;
}

// ---- MFMA GEMM: C[1024][2048] = A[1024][512]bf16 @ BT[2048][512]^T (+bias) ----
// 64x128 tile -> grid 16x16 = 256 blocks (1/CU). 4 waves: 2(M-half 32) x 2(N-half 64).
__global__ __launch_bounds__(256)
void gemm_bf16(const unsigned short* __restrict__ A,
               const unsigned short* __restrict__ BT,
               const float* __restrict__ bias,
               float* __restrict__ C){
    __shared__ short As[TM*LDA];
    __shared__ short Bs[TN*LDA];
    int bn = blockIdx.x, bm = blockIdx.y;
    int tid = threadIdx.x;
    int lane = tid & 63, wave = tid >> 6;
    int wm = wave & 1, wn = wave >> 1;
    int lm = lane & 15, quad = lane >> 4;
    v4f acc[2][4];
    #pragma unroll
    for (int i=0;i<2;++i)
        #pragma unroll
        for (int j=0;j<4;++j) acc[i][j] = (v4f)0.0f;

    int srow = tid >> 3, scol = (tid & 7)*8;     // 32 rows x 64 k per pass
    for (int k0 = 0; k0 < KD; k0 += 64){
        __syncthreads();
        #pragma unroll
        for (int pass = 0; pass < 2; ++pass){
            int row = pass*32 + srow;
            v8s a = *(const v8s*)(A + (size_t)(bm*TM+row)*KD + k0 + scol);
            *(v8s*)&As[row*LDA + scol] = a;
        }
        #pragma unroll
        for (int pass = 0; pass < 4; ++pass){
            int row = pass*32 + srow;
            v8s b = *(const v8s*)(BT + (size_t)(bn*TN+row)*KD + k0 + scol);
            *(v8s*)&Bs[row*LDA + scol] = b;
        }
        __syncthreads();
        #pragma unroll
        for (int kk = 0; kk < 64; kk += 32){
            v8s af[2], bf[4];
            #pragma unroll
            for (int i = 0; i < 2; ++i)
                af[i] = *(const v8s*)&As[(wm*32 + i*16 + lm)*LDA + kk + quad*8];
            #pragma unroll
            for (int j = 0; j < 4; ++j)
                bf[j] = *(const v8s*)&Bs[(wn*64 + j*16 + lm)*LDA + kk + quad*8];
            #pragma unroll
            for (int i = 0; i < 2; ++i)
                #pragma unroll
                for (int j = 0; j < 4; ++j)
                    acc[i][j] = __builtin_amdgcn_mfma_f32_16x16x32_bf16(af[i], bf[j], acc[i][j], 0, 0, 0);
        }
    }
    #pragma unroll
    for (int j = 0; j < 4; ++j){
        int n = bn*TN + wn*64 + j*16 + lm;
        float bv = bias ? bias[n] : 0.0f;
        #pragma unroll
        for (int i = 0; i < 2; ++i){
            int m0 = bm*TM + wm*32 + i*16 + quad*4;
            #pragma unroll
            for (int rg = 0; rg < 4; ++rg)
                C[(size_t)(m0+rg)*N2 + n] = acc[i][j][rg] + bv;
        }
    }
}

// ---- fused per-step epilogue: CSR-gathered scatters + gates + masked-scatter ----
// T row: [iou_hr_i | iou_hl_i | fh_r | fh_l]; XO row: [iou_i | iou_o | iou_u | fx_x]
__global__ __launch_bounds__(256)
void step_fused(const float* __restrict__ XO, const float* __restrict__ T,
                const float* __restrict__ h_old, const float* __restrict__ c_old,
                float* __restrict__ h_new, float* __restrict__ c_new,
                unsigned short* __restrict__ hb,
                const int* __restrict__ msk, const int* __restrict__ rnk,
                const int* __restrict__ cnt, const int* __restrict__ off,
                const int* __restrict__ ent, int st){
    int r = blockIdx.x;
    if (!msk[st*R_ + r]){
        for (int c = threadIdx.x; c < H_; c += 256){
            float hv = h_old[(size_t)r*H_ + c];
            h_new[(size_t)r*H_ + c] = hv;
            c_new[(size_t)r*H_ + c] = c_old[(size_t)r*H_ + c];
            hb[(size_t)r*KD + c] = f2b(hv);
        }
        return;
    }
    int j = rnk[st*R_ + r];   // compacted source row: compute h_full[j]
    int bR = off[(0*NST + st)*R_ + j], dR = cnt[(0*NST + st)*R_ + j];
    int bL = off[(1*NST + st)*R_ + j], dL = cnt[(1*NST + st)*R_ + j];
    int bD = off[(2*NST + st)*R_ + j], dD = cnt[(2*NST + st)*R_ + j];
    const int* eR = ent + (0*NST + st)*R_ + bR;
    const int* eL = ent + (1*NST + st)*R_ + bL;
    const int* eD = ent + (2*NST + st)*R_ + bD;
    const float* xo = XO + (size_t)j*N2;
    for (int c = threadIdx.x; c < H_; c += 256){
        float scat = 0.f;
        for (int e = 0; e < dR; ++e) scat += T[(size_t)eR[e]*N2 + c];
        for (int e = 0; e < dL; ++e) scat += T[(size_t)eL[e]*N2 + 512 + c];
        float fxv = xo[1536 + c];
        float csc = 0.f;
        for (int e = 0; e < dD; ++e){
            int pk = eD[e];
            int s  = pk & 1023, rr = (pk >> 10) & 1023, rl = (pk >> 20) & 1023;
            float f = sigm(fxv + T[(size_t)rr*N2 + 1024 + c] + T[(size_t)rl*N2 + 1536 + c]);
            csc += f * c_old[(size_t)s*H_ + c];
        }
        float ig = sigm(xo[c] + scat);
        float og = sigm(xo[512 + c]);
        float ug = tanhf(xo[1024 + c]);
        float cf = ig*ug + csc;
        float hf = og * tanhf(cf);
        h_new[(size_t)r*H_ + c] = hf;
        c_new[(size_t)r*H_ + c] = cf;
        hb[(size_t)r*KD + c] = f2b(hf);
    }
}

extern "C" void kernel_launch(void* const* d_in, const int* in_sizes, int n_in,
                              void* d_out, int out_size, void* d_ws, size_t ws_size,
                              hipStream_t stream) {
    const int* input_ids = (const int*)d_in[0];
    const int* tree      = (const int*)d_in[1];

    char* p = (char*)d_ws;
    auto alloc = [&](size_t bytes) -> void* {
        void* q = (void*)p;
        p += (bytes + 255) & ~(size_t)255;
        return q;
    };
    float*          XO     = (float*)alloc((size_t)R_*N2*4);           // 8 MB
    float*          T      = (float*)alloc((size_t)R_*N2*4);           // 8 MB
    float*          h0     = (float*)alloc((size_t)R_*H_*4);           // contig with c0
    float*          c0     = (float*)alloc((size_t)R_*H_*4);
    float*          h1     = (float*)alloc((size_t)R_*H_*4);
    float*          c1     = (float*)alloc((size_t)R_*H_*4);
    unsigned short* WxT    = (unsigned short*)alloc((size_t)N2*KD*2);  // 2 MB
    unsigned short* WcatT  = (unsigned short*)alloc((size_t)N2*KD*2);  // 2 MB
    float*          bcat   = (float*)alloc((size_t)N2*4);
    unsigned short* xb     = (unsigned short*)alloc((size_t)R_*KD*2);  // 1 MB
    unsigned short* hb     = (unsigned short*)alloc((size_t)R_*KD*2);  // 1 MB
    int*            msk    = (int*)alloc((size_t)NST*R_*4);
    int*            rnk    = (int*)alloc((size_t)NST*R_*4);
    int*            cnt    = (int*)alloc((size_t)3*NST*R_*4);          // 96 KB
    int*            off    = (int*)alloc((size_t)3*NST*R_*4);
    int*            cur    = (int*)alloc((size_t)3*NST*R_*4);
    int*            ent    = (int*)alloc((size_t)3*NST*R_*4);
    int*            flags  = (int*)alloc(256);

    hipLaunchKernelGGL(probe_f, dim3(15), dim3(512), 0, stream,
                       d_in[2], d_in[3], d_in[4], d_in[5], d_in[6], d_in[7], d_in[8],
                       d_in[9], d_in[10], d_in[11], d_in[12], d_in[13], d_in[14],
                       d_in[15], d_in[16], flags);
    hipLaunchKernelGGL(probe_i, dim3(2), dim3(1024), 0, stream, input_ids, tree, flags);
    hipLaunchKernelGGL(rank_kernel, dim3(NST), dim3(R_), 0, stream, tree, msk, rnk, flags);
    hipMemsetAsync(cnt, 0, (size_t)3*NST*R_*4, stream);
    hipLaunchKernelGGL(csr_count, dim3(NST), dim3(R_), 0, stream, tree, cnt, flags);
    hipLaunchKernelGGL(csr_scan, dim3(NST, 3), dim3(R_), 0, stream, cnt, off, cur);
    hipLaunchKernelGGL(csr_fill, dim3(NST), dim3(R_), 0, stream, tree, cur, ent, flags);
    hipLaunchKernelGGL(pack_wxt, dim3(8, 64), dim3(256), 0, stream,
                       d_in[3], d_in[8], WxT, flags);
    hipLaunchKernelGGL(pack_wcatt, dim3(8, 64), dim3(256), 0, stream,
                       d_in[4], d_in[6], d_in[9], d_in[11], d_in[13], d_in[15], WcatT, flags);
    hipLaunchKernelGGL(pack_bcat, dim3(8), dim3(256), 0, stream,
                       d_in[5], d_in[7], d_in[10], d_in[12], d_in[14], d_in[16], bcat, flags);
    hipLaunchKernelGGL(gather_xb, dim3(R_*KD/8/256), dim3(256), 0, stream,
                       input_ids, d_in[2], xb, flags);
    hipMemsetAsync(h0, 0, (size_t)2*R_*H_*4, stream);   // h0 and c0
    hipMemsetAsync(hb, 0, (size_t)R_*KD*2, stream);     // bf16 h for step 0

    // XO = xb @ WxT^T  (1024 x 2048, K=512), no bias
    hipLaunchKernelGGL(gemm_bf16, dim3(N2/TN, R_/TM), dim3(256), 0, stream,
                       xb, WxT, (const float*)nullptr, XO);

    float *hc = h0, *cc = c0, *hn = h1, *cn = c1;
    for (int st = 0; st < NST; ++st){
        hipLaunchKernelGGL(gemm_bf16, dim3(N2/TN, R_/TM), dim3(256), 0, stream,
                           hb, WcatT, bcat, T);
        hipLaunchKernelGGL(step_fused, dim3(R_), dim3(256), 0, stream,
                           XO, T, hc, cc, hn, cn, hb, msk, rnk, cnt, off, ent, st);
        float* th = hc; hc = hn; hn = th;
        float* tc = cc; cc = cn; cn = tc;
    }
    // output is fp32 (verified r4)
    hipMemcpyAsync(d_out, hc, (size_t)R_*H_*4, hipMemcpyDeviceToDevice, stream);
}

// Round 7
// 324.845 us; speedup vs baseline: 1.3325x; 1.3325x over previous
//
#include <hip/hip_runtime.h>
#include <hip/hip_bf16.h>

#define B_ 8
#define S_ 128
#define H_ 512
#define E_ 512
#define NST 8
#define R_ 1024         // flat rows
#define N2 2048         // packed GEMM width / T,XO row width
#define KD 512          // GEMM K depth
#define LDA 72          // LDS row pitch in shorts (fragment ds_read_b128: 2-way = free)
#define TM 64
#define TN 64

typedef __hip_bfloat16 bf16;
typedef __attribute__((ext_vector_type(8))) short v8s;
typedef __attribute__((ext_vector_type(4))) float v4f;

__device__ __forceinline__ float sigm(float x){ return 1.0f/(1.0f + expf(-x)); }
__device__ __forceinline__ float load_in(const void* p, long long i, int isb){
    return isb ? __bfloat162float(((const bf16*)p)[i]) : ((const float*)p)[i];
}
__device__ __forceinline__ int idx_read(const int* p, int j, int is64){
    return is64 ? p[2*j] : p[j];
}
__device__ __forceinline__ unsigned short f2b(float v){
    bf16 b = __float2bfloat16(v);
    return *(unsigned short*)&b;
}

// ---- merged dtype probes: bid 0..14 float tensors, bid 15/16 int tensors ----
__global__ void probe_all(const void* t0, const void* t1, const void* t2, const void* t3,
                          const void* t4, const void* t5, const void* t6, const void* t7,
                          const void* t8, const void* t9, const void* t10, const void* t11,
                          const void* t12, const void* t13, const void* t14,
                          const int* __restrict__ ids, const int* __restrict__ tree,
                          int* __restrict__ flags){
    const void* ts[15] = {t0,t1,t2,t3,t4,t5,t6,t7,t8,t9,t10,t11,t12,t13,t14};
    int bid = blockIdx.x, t = threadIdx.x;   // 1024 threads
    int bad = 0;
    if (bid < 15){
        if (t < 512){
            unsigned short u = ((const unsigned short*)ts[bid])[t];
            bad = (((u >> 7) & 0xFF) >= 140);
        }
    } else {
        const int* p = (bid == 15) ? ids : tree;
        int n = (bid == 15) ? 1024 : 2048;
        for (int j = t; j < n; j += 1024)
            if (j & 1) bad |= (p[j] != 0);
    }
    unsigned long long bl = __ballot(bad);
    __shared__ int acc[16];
    if ((t & 63) == 0) acc[t >> 6] = (bl != 0ull) ? 1 : 0;
    __syncthreads();
    if (t == 0){
        int any = 0;
        for (int w = 0; w < 16; ++w) any |= acc[w];
        // float: any-huge -> fp32 (flag 0); int: all-odd-zero -> int64 (flag 1)
        flags[(bid < 15) ? bid : (16 + bid - 15)] = (bid < 15) ? (any ? 0 : 1) : (any ? 0 : 1);
    }
}

// ---- mask+rank (global compaction order) + CSR counts, cnt self-zeroed ----
__global__ void rank_count(const int* __restrict__ tree, int* __restrict__ msk,
                           int* __restrict__ rnk, int* __restrict__ cnt,
                           const int* __restrict__ flags){
    int is64 = flags[17];
    int st = blockIdx.x;
    int t  = threadIdx.x;                 // 0..1023 == b*S+s
    cnt[(0*NST + st)*R_ + t] = 0;
    cnt[(1*NST + st)*R_ + t] = 0;
    cnt[(2*NST + st)*R_ + t] = 0;
    __syncthreads();
    int b = t >> 7, s = t & 127;
    int base = (b*NST + st)*3*S_;
    int d0 = idx_read(tree, base + s, is64);
    int rd = (b<<7) + d0;
    int rr = (b<<7) + idx_read(tree, base + S_ + s, is64);
    int rl = (b<<7) + idx_read(tree, base + 2*S_ + s, is64);
    int m = (d0 != 0) ? 1 : 0;
    unsigned long long bal = __ballot(m);
    int lane = t & 63, wave = t >> 6;
    __shared__ int wtot[16];
    if (lane == 0) wtot[wave] = __popcll(bal);
    __syncthreads();
    int bp = 0;
    for (int w = 0; w < wave; ++w) bp += wtot[w];
    int rank = bp + __popcll(bal & ((1ull << lane) - 1ull));
    msk[st*R_ + t] = m;
    rnk[st*R_ + t] = m ? rank : 0;
    atomicAdd(&cnt[(0*NST + st)*R_ + rr], 1);
    atomicAdd(&cnt[(1*NST + st)*R_ + rl], 1);
    atomicAdd(&cnt[(2*NST + st)*R_ + rd], 1);
}

__global__ void csr_scan(const int* __restrict__ cnt, int* __restrict__ off,
                         int* __restrict__ cur){
    int st = blockIdx.x, a = blockIdx.y;
    int t = threadIdx.x;   // 1024
    int base = (a*NST + st)*R_;
    __shared__ int sh[R_];
    int v = cnt[base + t];
    sh[t] = v;
    __syncthreads();
    for (int d = 1; d < R_; d <<= 1){
        int x = (t >= d) ? sh[t - d] : 0;
        __syncthreads();
        sh[t] += x;
        __syncthreads();
    }
    int excl = sh[t] - v;
    off[base + t] = excl;
    cur[base + t] = excl;
}

__global__ void csr_fill(const int* __restrict__ tree, int* __restrict__ cur,
                         int* __restrict__ ent, const int* __restrict__ flags){
    int is64 = flags[17];
    int st = blockIdx.x;
    int t = threadIdx.x;   // 1024
    int b = t >> 7, s = t & 127;
    int base = (b*NST + st)*3*S_;
    int rd = (b<<7) + idx_read(tree, base + s, is64);
    int rr = (b<<7) + idx_read(tree, base + S_ + s, is64);
    int rl = (b<<7) + idx_read(tree, base + 2*S_ + s, is64);
    int p0 = atomicAdd(&cur[(0*NST + st)*R_ + rr], 1);
    ent[(0*NST + st)*R_ + p0] = t;
    int p1 = atomicAdd(&cur[(1*NST + st)*R_ + rl], 1);
    ent[(1*NST + st)*R_ + p1] = t;
    int p2 = atomicAdd(&cur[(2*NST + st)*R_ + rd], 1);
    ent[(2*NST + st)*R_ + p2] = t | (rr << 10) | (rl << 20);
}

// ---- merged one-time packs + zero-init (multi-region by blockIdx) ----
// R0 [0,512): WxT       R1 [512,1024): WcatT   R2 [1024,1032): bcat
// R3 [1032,1288): xb    R4 [1288,2312): zero h0/c0 (4 MB)   R5 [2312,2568): zero hb
__global__ __launch_bounds__(256)
void pack_all(const void* __restrict__ Wioux, const void* __restrict__ Wfx,
              const void* __restrict__ Wr, const void* __restrict__ Wl,
              const void* __restrict__ W0, const void* __restrict__ W1,
              const void* __restrict__ W2, const void* __restrict__ W3,
              const void* __restrict__ br, const void* __restrict__ bl,
              const void* __restrict__ b0, const void* __restrict__ b1,
              const void* __restrict__ b2, const void* __restrict__ b3,
              const int* __restrict__ ids, const void* __restrict__ emb,
              unsigned short* __restrict__ WxT, unsigned short* __restrict__ WcatT,
              float* __restrict__ bcat, unsigned short* __restrict__ xb,
              float* __restrict__ h0, unsigned short* __restrict__ hb,
              const int* __restrict__ flags){
    int bid = blockIdx.x, tid = threadIdx.x;
    if (bid < 512){
        int f_wx = flags[1], f_wf = flags[6];
        int n = (bid & 7)*256 + tid;
        int k0 = (bid >> 3)*8;
        unsigned short tmp[8];
        #pragma unroll
        for (int i = 0; i < 8; ++i){
            float v = (n < 1536) ? load_in(Wioux, (long long)(k0+i)*1536 + n, f_wx)
                                 : load_in(Wfx,   (long long)(k0+i)*512 + (n-1536), f_wf);
            tmp[i] = f2b(v);
        }
        *(v8s*)&WxT[(size_t)n*KD + k0] = *(v8s*)tmp;
    } else if (bid < 1024){
        int fWr=flags[2], fWl=flags[4], fW0=flags[7], fW1=flags[9], fW2=flags[11], fW3=flags[13];
        int bb = bid - 512;
        int n = (bb & 7)*256 + tid;
        int k0 = (bb >> 3)*8;
        unsigned short tmp[8];
        #pragma unroll
        for (int i = 0; i < 8; ++i){
            long long k = k0 + i;
            float v;
            if      (n <  512) v = load_in(Wr, k*1536 + n, fWr);
            else if (n < 1024) v = load_in(Wl, k*1536 + (n-512), fWl);
            else if (n < 1536) { int c = n-1024; v = load_in(W0, k*512+c, fW0) + load_in(W1, k*512+c, fW1); }
            else               { int c = n-1536; v = load_in(W2, k*512+c, fW2) + load_in(W3, k*512+c, fW3); }
            tmp[i] = f2b(v);
        }
        *(v8s*)&WcatT[(size_t)n*KD + k0] = *(v8s*)tmp;
    } else if (bid < 1032){
        int fbr=flags[3], fbl=flags[5], fb0=flags[8], fb1=flags[10], fb2=flags[12], fb3=flags[14];
        int n = (bid - 1024)*256 + tid;
        float v;
        if      (n <  512) v = load_in(br, n, fbr);
        else if (n < 1024) v = load_in(bl, n-512, fbl);
        else if (n < 1536) v = load_in(b0, n-1024, fb0) + load_in(b1, n-1024, fb1);
        else               v = load_in(b2, n-1536, fb2) + load_in(b3, n-1536, fb3);
        bcat[n] = v;
    } else if (bid < 1288){
        int f_emb = flags[0], i64 = flags[16];
        int id = (bid - 1032)*256 + tid;
        int r = id >> 6, c0 = (id & 63)*8;
        long long base = (long long)idx_read(ids, r, i64)*E_ + c0;
        unsigned short tmp[8];
        #pragma unroll
        for (int i = 0; i < 8; ++i) tmp[i] = f2b(load_in(emb, base + i, f_emb));
        *(v8s*)&xb[(size_t)r*KD + c0] = *(v8s*)tmp;
    } else if (bid < 2312){
        int idx = (bid - 1288)*256 + tid;     // h0+c0 contiguous: 1Mi floats
        ((float4*)h0)[idx] = make_float4(0.f, 0.f, 0.f, 0.f);
    } else {
        int idx = (bid - 2312)*256 + tid;     // hb: 512Ki shorts = 64Ki float4
        ((float4*)hb)[idx] = make_float4(0.f, 0.f, 0.f, 0.f);
    }
}

// ---- MFMA GEMM: C[1024][2048] = A[1024][512]bf16 @ BT[2048][512]^T (+bias) ----
// 64x64 tile, grid (32,16)=512 blocks = 2/CU (8 waves/CU), software-prefetched staging.
__global__ __launch_bounds__(256)
void gemm_bf16(const unsigned short* __restrict__ A,
               const unsigned short* __restrict__ BT,
               const float* __restrict__ bias,
               float* __restrict__ C){
    __shared__ short As[TM*LDA];
    __shared__ short Bs[TN*LDA];
    int bn = blockIdx.x, bm = blockIdx.y;
    int tid = threadIdx.x;
    int lane = tid & 63, wave = tid >> 6;     // 4 waves, 2x2 of 32x32
    int wm = wave & 1, wn = wave >> 1;
    int lm = lane & 15, quad = lane >> 4;
    v4f acc[2][2];
    #pragma unroll
    for (int i=0;i<2;++i)
        #pragma unroll
        for (int j=0;j<2;++j) acc[i][j] = (v4f)0.0f;

    int srow = tid >> 3, sg = (tid & 7)*8;    // staging: 2 A rows + 2 B rows per thread
    const unsigned short* Ab = A  + (size_t)(bm*TM)*KD;
    const unsigned short* Bb = BT + (size_t)(bn*TN)*KD;
    v8s pa[2], pb[2];
    #pragma unroll
    for (int j=0;j<2;++j){
        pa[j] = *(const v8s*)(Ab + (size_t)(j*32+srow)*KD + sg);
        pb[j] = *(const v8s*)(Bb + (size_t)(j*32+srow)*KD + sg);
    }
    for (int k0 = 0; k0 < KD; k0 += 64){
        #pragma unroll
        for (int j=0;j<2;++j){
            *(v8s*)&As[(j*32+srow)*LDA + sg] = pa[j];
            *(v8s*)&Bs[(j*32+srow)*LDA + sg] = pb[j];
        }
        __syncthreads();
        int k1 = k0 + 64;
        if (k1 < KD){
            #pragma unroll
            for (int j=0;j<2;++j){      // prefetch overlaps the MFMA phase below
                pa[j] = *(const v8s*)(Ab + (size_t)(j*32+srow)*KD + k1 + sg);
                pb[j] = *(const v8s*)(Bb + (size_t)(j*32+srow)*KD + k1 + sg);
            }
        }
        #pragma unroll
        for (int kk = 0; kk < 64; kk += 32){
            v8s af[2], bf[2];
            #pragma unroll
            for (int i=0;i<2;++i){
                af[i] = *(const v8s*)&As[(wm*32 + i*16 + lm)*LDA + kk + quad*8];
                bf[i] = *(const v8s*)&Bs[(wn*32 + i*16 + lm)*LDA + kk + quad*8];
            }
            #pragma unroll
            for (int i=0;i<2;++i)
                #pragma unroll
                for (int j=0;j<2;++j)
                    acc[i][j] = __builtin_amdgcn_mfma_f32_16x16x32_bf16(af[i], bf[j], acc[i][j], 0, 0, 0);
        }
        __syncthreads();
    }
    #pragma unroll
    for (int j=0;j<2;++j){
        int n = bn*TN + wn*32 + j*16 + lm;
        float bv = bias ? bias[n] : 0.0f;
        #pragma unroll
        for (int i=0;i<2;++i){
            int m0 = bm*TM + wm*32 + i*16 + quad*4;
            #pragma unroll
            for (int rg = 0; rg < 4; ++rg)
                C[(size_t)(m0+rg)*N2 + n] = acc[i][j][rg] + bv;
        }
    }
}

// ---- fused per-step epilogue: CSR-gathered scatters + gates + masked-scatter ----
// T row: [iou_hr_i | iou_hl_i | fh_r | fh_l]; XO row: [iou_i | iou_o | iou_u | fx_x]
__global__ __launch_bounds__(256)
void step_fused(const float* __restrict__ XO, const float* __restrict__ T,
                const float* __restrict__ h_old, const float* __restrict__ c_old,
                float* __restrict__ h_new, float* __restrict__ c_new,
                unsigned short* __restrict__ hb,
                const int* __restrict__ msk, const int* __restrict__ rnk,
                const int* __restrict__ cnt, const int* __restrict__ off,
                const int* __restrict__ ent, int st){
    int r = blockIdx.x;
    if (!msk[st*R_ + r]){
        for (int c = threadIdx.x; c < H_; c += 256){
            float hv = h_old[(size_t)r*H_ + c];
            h_new[(size_t)r*H_ + c] = hv;
            c_new[(size_t)r*H_ + c] = c_old[(size_t)r*H_ + c];
            hb[(size_t)r*KD + c] = f2b(hv);
        }
        return;
    }
    int j = rnk[st*R_ + r];   // compacted source row: compute h_full[j]
    int bR = off[(0*NST + st)*R_ + j], dR = cnt[(0*NST + st)*R_ + j];
    int bL = off[(1*NST + st)*R_ + j], dL = cnt[(1*NST + st)*R_ + j];
    int bD = off[(2*NST + st)*R_ + j], dD = cnt[(2*NST + st)*R_ + j];
    const int* eR = ent + (0*NST + st)*R_ + bR;
    const int* eL = ent + (1*NST + st)*R_ + bL;
    const int* eD = ent + (2*NST + st)*R_ + bD;
    const float* xo = XO + (size_t)j*N2;
    for (int c = threadIdx.x; c < H_; c += 256){
        float scat = 0.f;
        for (int e = 0; e < dR; ++e) scat += T[(size_t)eR[e]*N2 + c];
        for (int e = 0; e < dL; ++e) scat += T[(size_t)eL[e]*N2 + 512 + c];
        float fxv = xo[1536 + c];
        float csc = 0.f;
        for (int e = 0; e < dD; ++e){
            int pk = eD[e];
            int s  = pk & 1023, rr = (pk >> 10) & 1023, rl = (pk >> 20) & 1023;
            float f = sigm(fxv + T[(size_t)rr*N2 + 1024 + c] + T[(size_t)rl*N2 + 1536 + c]);
            csc += f * c_old[(size_t)s*H_ + c];
        }
        float ig = sigm(xo[c] + scat);
        float og = sigm(xo[512 + c]);
        float ug = tanhf(xo[1024 + c]);
        float cf = ig*ug + csc;
        float hf = og * tanhf(cf);
        h_new[(size_t)r*H_ + c] = hf;
        c_new[(size_t)r*H_ + c] = cf;
        hb[(size_t)r*KD + c] = f2b(hf);
    }
}

extern "C" void kernel_launch(void* const* d_in, const int* in_sizes, int n_in,
                              void* d_out, int out_size, void* d_ws, size_t ws_size,
                              hipStream_t stream) {
    const int* input_ids = (const int*)d_in[0];
    const int* tree      = (const int*)d_in[1];

    char* p = (char*)d_ws;
    auto alloc = [&](size_t bytes) -> void* {
        void* q = (void*)p;
        p += (bytes + 255) & ~(size_t)255;
        return q;
    };
    float*          XO     = (float*)alloc((size_t)R_*N2*4);           // 8 MB
    float*          T      = (float*)alloc((size_t)R_*N2*4);           // 8 MB
    float*          h0     = (float*)alloc((size_t)R_*H_*4);           // contig with c0
    float*          c0     = (float*)alloc((size_t)R_*H_*4);
    float*          h1     = (float*)alloc((size_t)R_*H_*4);
    float*          c1     = (float*)alloc((size_t)R_*H_*4);
    unsigned short* WxT    = (unsigned short*)alloc((size_t)N2*KD*2);  // 2 MB
    unsigned short* WcatT  = (unsigned short*)alloc((size_t)N2*KD*2);  // 2 MB
    float*          bcat   = (float*)alloc((size_t)N2*4);
    unsigned short* xb     = (unsigned short*)alloc((size_t)R_*KD*2);  // 1 MB
    unsigned short* hb     = (unsigned short*)alloc((size_t)R_*KD*2);  // 1 MB
    int*            msk    = (int*)alloc((size_t)NST*R_*4);
    int*            rnk    = (int*)alloc((size_t)NST*R_*4);
    int*            cnt    = (int*)alloc((size_t)3*NST*R_*4);
    int*            off    = (int*)alloc((size_t)3*NST*R_*4);
    int*            cur    = (int*)alloc((size_t)3*NST*R_*4);
    int*            ent    = (int*)alloc((size_t)3*NST*R_*4);
    int*            flags  = (int*)alloc(256);

    hipLaunchKernelGGL(probe_all, dim3(17), dim3(1024), 0, stream,
                       d_in[2], d_in[3], d_in[4], d_in[5], d_in[6], d_in[7], d_in[8],
                       d_in[9], d_in[10], d_in[11], d_in[12], d_in[13], d_in[14],
                       d_in[15], d_in[16], input_ids, tree, flags);
    hipLaunchKernelGGL(rank_count, dim3(NST), dim3(R_), 0, stream, tree, msk, rnk, cnt, flags);
    hipLaunchKernelGGL(csr_scan, dim3(NST, 3), dim3(R_), 0, stream, cnt, off, cur);
    hipLaunchKernelGGL(csr_fill, dim3(NST), dim3(R_), 0, stream, tree, cur, ent, flags);
    hipLaunchKernelGGL(pack_all, dim3(2568), dim3(256), 0, stream,
                       d_in[3], d_in[8],
                       d_in[4], d_in[6], d_in[9], d_in[11], d_in[13], d_in[15],
                       d_in[5], d_in[7], d_in[10], d_in[12], d_in[14], d_in[16],
                       input_ids, d_in[2],
                       WxT, WcatT, bcat, xb, h0, hb, flags);

    // XO = xb @ WxT^T  (1024 x 2048, K=512), no bias
    hipLaunchKernelGGL(gemm_bf16, dim3(N2/TN, R_/TM), dim3(256), 0, stream,
                       xb, WxT, (const float*)nullptr, XO);

    float *hc = h0, *cc = c0, *hn = h1, *cn = c1;
    for (int st = 0; st < NST; ++st){
        hipLaunchKernelGGL(gemm_bf16, dim3(N2/TN, R_/TM), dim3(256), 0, stream,
                           hb, WcatT, bcat, T);
        hipLaunchKernelGGL(step_fused, dim3(R_), dim3(256), 0, stream,
                           XO, T, hc, cc, hn, cn, hb, msk, rnk, cnt, off, ent, st);
        float* th = hc; hc = hn; hn = th;
        float* tc = cc; cc = cn; cn = tc;
    }
    // output is fp32 (verified r4)
    hipMemcpyAsync(d_out, hc, (size_t)R_*H_*4, hipMemcpyDeviceToDevice, stream);
}